// Round 3
// baseline (31.478 us; speedup 1.0000x reference)
//
#include <hip/hip_runtime.h>
#include <math.h>

// out[0][i]   = (floor((x[i]/max(x))*255) == t) ? weight[0][i] : 0
// out[r>0][*] = 0
//
// Single fused kernel (saves one graph node vs memset+row0):
//  - block 0:        max-reduce over x, then row-0 mask*weight (tiny, ~2us)
//  - blocks 1..N:    nontemporal float4 zero-fill of rows 1.. (128 MiB).
//    NT stores bypass L2 (single-use write stream; regular stores thrashed
//    L2 and only hit ~4.2 TB/s in round 0; rocclr's fill does ~7.2 TB/s).
typedef float f4 __attribute__((ext_vector_type(4)));

__global__ __launch_bounds__(256) void TemporalEncoder_69707319214330_fused(
    const float* __restrict__ x,
    const float* __restrict__ w,
    const int* __restrict__ t_ptr,
    float* __restrict__ out,
    int in_f,
    int total_vec)   // total elements / 4 (fits int32: 8.39M)
{
    const int tid = threadIdx.x;
    const int nvec = in_f >> 2;              // 2048 float4 in row 0

    if (blockIdx.x == 0) {
        // ---- row 0: max(x) then mask*weight, 256 threads ----
        const float4* x4 = reinterpret_cast<const float4*>(x);
        float m = -INFINITY;
        for (int i = tid; i < nvec; i += 256) {
            const float4 v = x4[i];
            m = fmaxf(m, fmaxf(fmaxf(v.x, v.y), fmaxf(v.z, v.w)));
        }
        for (int off = 32; off > 0; off >>= 1)
            m = fmaxf(m, __shfl_down(m, off, 64));
        __shared__ float smax[4];
        if ((tid & 63) == 0) smax[tid >> 6] = m;
        __syncthreads();
        const float mx = fmaxf(fmaxf(smax[0], smax[1]), fmaxf(smax[2], smax[3]));
        const int t = *t_ptr;
        const float4* w4 = reinterpret_cast<const float4*>(w);
        float4* out4 = reinterpret_cast<float4*>(out);
        for (int i = tid; i < nvec; i += 256) {
            const float4 xv = x4[i];
            const float4 wv = w4[i];
            float4 o;
            // exact reference op order: (x / max) * 255 -> floor -> int == t
            o.x = ((int)floorf((xv.x / mx) * 255.0f) == t) ? wv.x : 0.0f;
            o.y = ((int)floorf((xv.y / mx) * 255.0f) == t) ? wv.y : 0.0f;
            o.z = ((int)floorf((xv.z / mx) * 255.0f) == t) ? wv.z : 0.0f;
            o.w = ((int)floorf((xv.w / mx) * 255.0f) == t) ? wv.w : 0.0f;
            out4[i] = o;
        }
        return;
    }

    // ---- blocks 1..N: nontemporal zero-fill of rows 1.. ----
    f4* o4 = reinterpret_cast<f4*>(out);
    const f4 z = {0.f, 0.f, 0.f, 0.f};
    const int stride = (gridDim.x - 1) * 256;
    for (int i = nvec + (blockIdx.x - 1) * 256 + tid; i < total_vec; i += stride) {
        __builtin_nontemporal_store(z, o4 + i);
    }
}

extern "C" void kernel_launch(void* const* d_in, const int* in_sizes, int n_in,
                              void* d_out, int out_size, void* d_ws, size_t ws_size,
                              hipStream_t stream) {
    const float* x = (const float*)d_in[0];
    const float* w = (const float*)d_in[1];
    const int*   t = (const int*)d_in[2];
    float* out = (float*)d_out;

    const int in_f = in_sizes[0];        // 8192
    const int total_vec = out_size >> 2; // 8,388,608 float4

    // 4096 fill blocks (~8 float4-iters each) + 1 row0 block
    TemporalEncoder_69707319214330_fused<<<dim3(4097), dim3(256), 0, stream>>>(
        x, w, t, out, in_f, total_vec);
}

// Round 4
// 27.169 us; speedup vs baseline: 1.1586x; 1.1586x over previous
//
#include <hip/hip_runtime.h>
#include <math.h>

// out[0][i]   = (floor((x[i]/max(x))*255) == t) ? weight[0][i] : 0
// out[r>0][*] = 0
//
// Structure (best measured, round 2): hipMemsetAsync for the 128 MiB bulk
// zero (rocclr fillBufferAligned sustains ~7.2 TB/s = write ceiling; our
// hand fills topped out at ~5.2 TB/s across two attempts), then a tiny
// row-0 kernel. This round: row0 uses 8 blocks with REDUNDANT max
// computation (x is 32 KB, L2-resident — cheaper to recompute per block
// than to sync across blocks), cutting its single-CU latency ~4us -> ~2us.
__global__ __launch_bounds__(256) void TemporalEncoder_69707319214330_row0(
    const float* __restrict__ x,
    const float* __restrict__ w,
    const int* __restrict__ t_ptr,
    float* __restrict__ out,
    int in_f)
{
    const int tid = threadIdx.x;
    const int nvec = in_f >> 2;                 // 2048 float4
    const float4* x4 = reinterpret_cast<const float4*>(x);

    // ---- per-block (redundant) max over all of x: 8 float4 loads/thread ----
    float m = -INFINITY;
    for (int i = tid; i < nvec; i += 256) {
        const float4 v = x4[i];
        m = fmaxf(m, fmaxf(fmaxf(v.x, v.y), fmaxf(v.z, v.w)));
    }
    for (int off = 32; off > 0; off >>= 1)
        m = fmaxf(m, __shfl_down(m, off, 64));
    __shared__ float smax[4];
    if ((tid & 63) == 0) smax[tid >> 6] = m;
    __syncthreads();
    const float mx = fmaxf(fmaxf(smax[0], smax[1]), fmaxf(smax[2], smax[3]));

    // ---- this block's 256-float4 slice of row 0 ----
    const int t = *t_ptr;
    const int i = blockIdx.x * 256 + tid;       // float4 index
    if (i < nvec) {
        const float4 xv = x4[i];
        const float4 wv = reinterpret_cast<const float4*>(w)[i];
        float4 o;
        // exact reference op order: (x / max) * 255 -> floor -> int == t
        o.x = ((int)floorf((xv.x / mx) * 255.0f) == t) ? wv.x : 0.0f;
        o.y = ((int)floorf((xv.y / mx) * 255.0f) == t) ? wv.y : 0.0f;
        o.z = ((int)floorf((xv.z / mx) * 255.0f) == t) ? wv.z : 0.0f;
        o.w = ((int)floorf((xv.w / mx) * 255.0f) == t) ? wv.w : 0.0f;
        reinterpret_cast<float4*>(out)[i] = o;
    }
    // scalar tail for in_f not divisible by 4 (unused at 8192)
    for (int s = nvec * 4 + blockIdx.x * 256 + tid; s < in_f; s += gridDim.x * 256)
        out[s] = ((int)floorf((x[s] / mx) * 255.0f) == t) ? w[s] : 0.0f;
}

extern "C" void kernel_launch(void* const* d_in, const int* in_sizes, int n_in,
                              void* d_out, int out_size, void* d_ws, size_t ws_size,
                              hipStream_t stream) {
    const float* x = (const float*)d_in[0];
    const float* w = (const float*)d_in[1];
    const int*   t = (const int*)d_in[2];
    float* out = (float*)d_out;

    const int in_f = in_sizes[0];                 // 8192
    const long long total = (long long)out_size;  // 4096 * 8192

    // Bulk zero of rows 1..end via the runtime's tuned fill kernel (~7.2 TB/s).
    hipMemsetAsync(out + in_f, 0, (size_t)(total - in_f) * sizeof(float), stream);

    // Row 0: 8 blocks, redundant max, one float4 per thread.
    const int nblk = ((in_f >> 2) + 255) / 256;   // 8 for in_f=8192
    TemporalEncoder_69707319214330_row0<<<dim3(nblk), dim3(256), 0, stream>>>(
        x, w, t, out, in_f);
}

// Round 5
// 23.063 us; speedup vs baseline: 1.3649x; 1.1781x over previous
//
#include <hip/hip_runtime.h>
#include <math.h>

// out[0][i]   = (floor((x[i]/max(x))*255) == t) ? weight[0][i] : 0
// out[r>0][*] = 0
//
// Single-dispatch design:
//  - block 0:           row 0 (redundant max over x + mask*weight) — runs
//                       CONCURRENTLY with the fill blocks (disjoint regions),
//                       so its ~2us hides under the 128 MiB fill.
//  - blocks 1..32760:   EXACTLY ONE zero float4 store each (exact-cover grid,
//                       no loop). Mimics rocclr fillBufferAligned's pattern
//                       (one wide store/thread, plain stores), which measures
//                       7.2 TB/s on this chip vs ~5 TB/s for my grid-stride
//                       loops in rounds 0/3.
__global__ __launch_bounds__(256) void TemporalEncoder_69707319214330_fused(
    const float* __restrict__ x,
    const float* __restrict__ w,
    const int* __restrict__ t_ptr,
    float* __restrict__ out,
    int in_f,
    int total_vec)   // out_size/4 = 8,388,608 (fits int32)
{
    const int tid = threadIdx.x;
    const int nvec = in_f >> 2;              // 2048 float4 in row 0

    if (blockIdx.x != 0) {
        // ---- fill: one float4 store per thread, exact cover of rows 1.. ----
        const int i = nvec + (int)(blockIdx.x - 1) * 256 + tid;
        if (i < total_vec) {
            float4 z = make_float4(0.f, 0.f, 0.f, 0.f);
            reinterpret_cast<float4*>(out)[i] = z;
        }
        return;
    }

    // ---- block 0: max(x) then row-0 mask*weight ----
    const float4* x4 = reinterpret_cast<const float4*>(x);
    float m = -INFINITY;
    for (int i = tid; i < nvec; i += 256) {
        const float4 v = x4[i];
        m = fmaxf(m, fmaxf(fmaxf(v.x, v.y), fmaxf(v.z, v.w)));
    }
    for (int off = 32; off > 0; off >>= 1)
        m = fmaxf(m, __shfl_down(m, off, 64));
    __shared__ float smax[4];
    if ((tid & 63) == 0) smax[tid >> 6] = m;
    __syncthreads();
    const float mx = fmaxf(fmaxf(smax[0], smax[1]), fmaxf(smax[2], smax[3]));

    const int t = *t_ptr;
    const float4* w4 = reinterpret_cast<const float4*>(w);
    float4* out4 = reinterpret_cast<float4*>(out);
    for (int i = tid; i < nvec; i += 256) {
        const float4 xv = x4[i];
        const float4 wv = w4[i];
        float4 o;
        // exact reference op order: (x / max) * 255 -> floor -> int == t
        o.x = ((int)floorf((xv.x / mx) * 255.0f) == t) ? wv.x : 0.0f;
        o.y = ((int)floorf((xv.y / mx) * 255.0f) == t) ? wv.y : 0.0f;
        o.z = ((int)floorf((xv.z / mx) * 255.0f) == t) ? wv.z : 0.0f;
        o.w = ((int)floorf((xv.w / mx) * 255.0f) == t) ? wv.w : 0.0f;
        out4[i] = o;
    }
    // scalar tail (unused at in_f=8192)
    for (int s = nvec * 4 + tid; s < in_f; s += 256)
        out[s] = ((int)floorf((x[s] / mx) * 255.0f) == t) ? w[s] : 0.0f;
}

extern "C" void kernel_launch(void* const* d_in, const int* in_sizes, int n_in,
                              void* d_out, int out_size, void* d_ws, size_t ws_size,
                              hipStream_t stream) {
    const float* x = (const float*)d_in[0];
    const float* w = (const float*)d_in[1];
    const int*   t = (const int*)d_in[2];
    float* out = (float*)d_out;

    const int in_f = in_sizes[0];         // 8192
    const int total_vec = out_size >> 2;  // 8,388,608 float4
    const int nvec = in_f >> 2;           // 2048

    // 1 row0 block + exact-cover fill blocks (one float4 store per thread)
    const int fill_blocks = (total_vec - nvec + 255) / 256;  // 32760
    TemporalEncoder_69707319214330_fused<<<dim3(fill_blocks + 1), dim3(256), 0, stream>>>(
        x, w, t, out, in_f, total_vec);
}